// Round 4
// baseline (322.224 us; speedup 1.0000x reference)
//
#include <hip/hip_runtime.h>

// BertCRF: emissions = hidden @ cls_w + cls_b ; CRF NLL (num - logZ), loss = -mean
// B=64 S=512 H=768 L=9
#define BB 64
#define SS 512
#define HH 768
#define LL 9
#define NROWS (BB * SS)
#define NCHUNK 16
#define CLEN 32   // SS / NCHUNK

#define L2E 1.4426950408889634f
#define LN2 0.6931471805599453f
#define NEGINF (-1e30f)

// ---------------------------------------------------------------------------
// Kernel 1: emissions GEMM — one lane per row. Each thread streams its own
// 768-float row (24 x 8 float4, 128B contiguous bursts -> full cache lines,
// L1 absorbs the lane-transpose; HBM reads each byte once). Weights are
// wave-uniform (index independent of lane) -> scalar/broadcast loads.
// 9 accumulators per lane. ZERO shuffles / LDS / barriers (R3's version was
// DS-pipe-bound on the cross-lane reduction).
// ---------------------------------------------------------------------------
__global__ __launch_bounds__(128) void emis_gemm(
    const float* __restrict__ hidden, const float* __restrict__ w,
    const float* __restrict__ bias, float* __restrict__ emis) {
  const int row = blockIdx.x * 128 + threadIdx.x;  // grid 256 x 128 = 32768 rows
  const float4* __restrict__ hp =
      reinterpret_cast<const float4*>(hidden + (size_t)row * HH);

  float acc[LL];
#pragma unroll
  for (int j = 0; j < LL; ++j) acc[j] = 0.f;

#pragma unroll 2
  for (int kb = 0; kb < 24; ++kb) {
    float4 h[8];
#pragma unroll
    for (int u = 0; u < 8; ++u) h[u] = hp[kb * 8 + u];
    const float* __restrict__ wb = w + kb * 8 * 4 * LL;  // wave-uniform
#pragma unroll
    for (int u = 0; u < 8; ++u) {
      const float* __restrict__ wq = wb + u * 4 * LL;
#pragma unroll
      for (int j = 0; j < LL; ++j)
        acc[j] += h[u].x * wq[j] + h[u].y * wq[j + LL] +
                  h[u].z * wq[j + 2 * LL] + h[u].w * wq[j + 3 * LL];
    }
  }
#pragma unroll
  for (int j = 0; j < LL; ++j)
    emis[(size_t)row * LL + j] = acc[j] + bias[j];
}

// ---------------------------------------------------------------------------
// Kernel 2: CRF chunk scan (stage 1). Grid = 64 batches x 16 chunks.
// Block = 128 threads (2 waves). Chunk 0: real alpha recursion for steps
// 1..31 from init = start + em[0]. Chunks c>0: 9x9 log-matrix product of
// steps [32c, 32c+32) via 9 basis-row recursions. Wave 0 rows 0..6
// (lanes r*9+j), wave 1 rows 7..8 (lanes 0..17). Masked step == identity.
// ---------------------------------------------------------------------------
__global__ __launch_bounds__(128) void crf_chunk(
    const float* __restrict__ emis, const int* __restrict__ msk,
    const float* __restrict__ startT, const float* __restrict__ trans,
    float* __restrict__ initv, float* __restrict__ Pmat) {
  __shared__ float em_lds[CLEN * LL];
  __shared__ int mk_lds[CLEN];
  const int b = blockIdx.x >> 4;
  const int c = blockIdx.x & 15;
  const int tid = threadIdx.x;
  const int lane = tid & 63;
  const int wid = tid >> 6;

  const float* src = emis + ((size_t)b * SS + c * CLEN) * LL;
  for (int i = tid; i < CLEN * LL; i += 128) em_lds[i] = src[i];
  for (int i = tid; i < CLEN; i += 128) mk_lds[i] = msk[b * SS + c * CLEN + i];
  __syncthreads();

  int rloc = lane / 9;
  int j = lane - rloc * 9;
  if (rloc > 6) { rloc = 6; j = 8; }  // lane 63 (inactive) kept in-bounds
  const int rbase = rloc * 9;
  const bool active = (wid == 0) ? (lane < 63) : (lane < 18);
  const int r = wid * 7 + rloc;  // global row this lane-group computes

  float Tc[LL];
#pragma unroll
  for (int i = 0; i < LL; ++i) Tc[i] = trans[i * LL + j];

  float s;
  if (c == 0) s = startT[j] + em_lds[j];
  else s = (j == r) ? 0.f : NEGINF;
  const int t0 = (c == 0) ? 1 : 0;

  for (int t = t0; t < CLEN; ++t) {
    const float emj = em_lds[t * LL + j];
    const int mt = mk_lds[t];
    const float s0 = __shfl(s, rbase + 0), s1 = __shfl(s, rbase + 1), s2 = __shfl(s, rbase + 2);
    const float s3 = __shfl(s, rbase + 3), s4 = __shfl(s, rbase + 4), s5 = __shfl(s, rbase + 5);
    const float s6 = __shfl(s, rbase + 6), s7 = __shfl(s, rbase + 7), s8 = __shfl(s, rbase + 8);
    const float a0 = s0 + Tc[0], a1 = s1 + Tc[1], a2 = s2 + Tc[2];
    const float a3 = s3 + Tc[3], a4 = s4 + Tc[4], a5 = s5 + Tc[5];
    const float a6 = s6 + Tc[6], a7 = s7 + Tc[7], a8 = s8 + Tc[8];
    const float m = fmaxf(fmaxf(fmaxf(fmaxf(a0, a1), fmaxf(a2, a3)),
                                fmaxf(fmaxf(a4, a5), fmaxf(a6, a7))), a8);
    const float e =
        ((exp2f((a0 - m) * L2E) + exp2f((a1 - m) * L2E)) +
         (exp2f((a2 - m) * L2E) + exp2f((a3 - m) * L2E))) +
        ((exp2f((a4 - m) * L2E) + exp2f((a5 - m) * L2E)) +
         (exp2f((a6 - m) * L2E) + exp2f((a7 - m) * L2E))) +
        exp2f((a8 - m) * L2E);
    const float snew = m + LN2 * log2f(e) + emj;
    s = mt ? snew : s;
  }

  if (active) {
    if (c == 0) {
      if (wid == 0 && lane < LL) initv[b * LL + j] = s;
    } else {
      Pmat[((size_t)b * NCHUNK + c) * 81 + r * LL + j] = s;
    }
  }
}

// ---------------------------------------------------------------------------
// Kernel 3: per-batch combine (stage 2) + numerator. One 64-thread block
// per batch. Numerator: wave-parallel over timesteps + butterfly reduce.
// Denominator: alpha = initv, then 15 sequential vector x log-matrix
// combines (P staged in LDS), then lse with end transitions.
// ---------------------------------------------------------------------------
__global__ __launch_bounds__(64) void crf_combine(
    const float* __restrict__ emis, const int* __restrict__ labels,
    const int* __restrict__ msk, const float* __restrict__ startT,
    const float* __restrict__ endT, const float* __restrict__ trans,
    const float* __restrict__ initv, const float* __restrict__ Pmat,
    float* __restrict__ llh) {
  __shared__ float Pl[15 * 81];
  const int b = blockIdx.x;
  const int lane = threadIdx.x;
  const float* __restrict__ emb = emis + (size_t)b * SS * LL;
  const int* __restrict__ lab = labels + b * SS;
  const int* __restrict__ mk = msk + b * SS;

  const float* Pb = Pmat + (size_t)b * NCHUNK * 81 + 81;
  for (int i = lane; i < 15 * 81; i += 64) Pl[i] = Pb[i];

  // ---- numerator ----
  float acc = 0.f;
  int msum = 0;
  for (int t = lane; t < SS; t += 64) {
    int tg = lab[t]; if (tg == -100) tg = 0;
    const int mt = mk[t];
    msum += mt;
    if (t == 0) {
      acc += startT[tg] + emb[tg];
    } else {
      int tp = lab[t - 1]; if (tp == -100) tp = 0;
      acc += (trans[tp * LL + tg] + emb[t * LL + tg]) * (float)mt;
    }
  }
#pragma unroll
  for (int off = 32; off; off >>= 1) {
    acc += __shfl_xor(acc, off);
    msum += __shfl_xor(msum, off);
  }
  const int seq_end = msum - 1;
  int lt = lab[seq_end]; if (lt == -100) lt = 0;
  const float num = acc + endT[lt];

  __syncthreads();

  // ---- denominator ----
  const int j = (lane < LL) ? lane : 8;
  float a = initv[b * LL + j];
#pragma unroll 1
  for (int c = 0; c < 15; ++c) {
    const float* P = &Pl[c * 81];
    const float s0 = __shfl(a, 0), s1 = __shfl(a, 1), s2 = __shfl(a, 2);
    const float s3 = __shfl(a, 3), s4 = __shfl(a, 4), s5 = __shfl(a, 5);
    const float s6 = __shfl(a, 6), s7 = __shfl(a, 7), s8 = __shfl(a, 8);
    const float a0 = s0 + P[0 * LL + j], a1 = s1 + P[1 * LL + j], a2 = s2 + P[2 * LL + j];
    const float a3 = s3 + P[3 * LL + j], a4 = s4 + P[4 * LL + j], a5 = s5 + P[5 * LL + j];
    const float a6 = s6 + P[6 * LL + j], a7 = s7 + P[7 * LL + j], a8 = s8 + P[8 * LL + j];
    const float m = fmaxf(fmaxf(fmaxf(fmaxf(a0, a1), fmaxf(a2, a3)),
                                fmaxf(fmaxf(a4, a5), fmaxf(a6, a7))), a8);
    const float e =
        ((exp2f((a0 - m) * L2E) + exp2f((a1 - m) * L2E)) +
         (exp2f((a2 - m) * L2E) + exp2f((a3 - m) * L2E))) +
        ((exp2f((a4 - m) * L2E) + exp2f((a5 - m) * L2E)) +
         (exp2f((a6 - m) * L2E) + exp2f((a7 - m) * L2E))) +
        exp2f((a8 - m) * L2E);
    a = m + LN2 * log2f(e);
  }
  a += endT[j];
  {
    const float s0 = __shfl(a, 0), s1 = __shfl(a, 1), s2 = __shfl(a, 2);
    const float s3 = __shfl(a, 3), s4 = __shfl(a, 4), s5 = __shfl(a, 5);
    const float s6 = __shfl(a, 6), s7 = __shfl(a, 7), s8 = __shfl(a, 8);
    const float m = fmaxf(fmaxf(fmaxf(fmaxf(s0, s1), fmaxf(s2, s3)),
                                fmaxf(fmaxf(s4, s5), fmaxf(s6, s7))), s8);
    const float e =
        ((exp2f((s0 - m) * L2E) + exp2f((s1 - m) * L2E)) +
         (exp2f((s2 - m) * L2E) + exp2f((s3 - m) * L2E))) +
        ((exp2f((s4 - m) * L2E) + exp2f((s5 - m) * L2E)) +
         (exp2f((s6 - m) * L2E) + exp2f((s7 - m) * L2E))) +
        exp2f((s8 - m) * L2E);
    const float denom = m + LN2 * log2f(e);
    if (lane == 0) llh[b] = num - denom;
  }
}

// ---------------------------------------------------------------------------
// Kernel 4: loss = -mean(llh)
// ---------------------------------------------------------------------------
__global__ __launch_bounds__(64) void finalize(const float* __restrict__ llh,
                                               float* __restrict__ out) {
  float v = llh[threadIdx.x];
#pragma unroll
  for (int off = 32; off; off >>= 1) v += __shfl_xor(v, off);
  if (threadIdx.x == 0) out[0] = -v * (1.0f / BB);
}

extern "C" void kernel_launch(void* const* d_in, const int* in_sizes, int n_in,
                              void* d_out, int out_size, void* d_ws, size_t ws_size,
                              hipStream_t stream) {
  const float* hidden = (const float*)d_in[0];
  const float* cls_w  = (const float*)d_in[1];
  const float* cls_b  = (const float*)d_in[2];
  const float* startT = (const float*)d_in[3];
  const float* endT   = (const float*)d_in[4];
  const float* trans  = (const float*)d_in[5];
  const int* labels   = (const int*)d_in[6];
  const int* amask    = (const int*)d_in[7];

  float* out = (float*)d_out;
  float* emis = out + 1;  // output layout: [loss][emissions B*S*L]

  float* llh = (float*)d_ws;            // 64
  float* initv = llh + 64;              // 64*9
  float* Pmat = initv + 64 * LL;        // 64*16*81

  emis_gemm<<<NROWS / 128, 128, 0, stream>>>(hidden, cls_w, cls_b, emis);
  crf_chunk<<<BB * NCHUNK, 128, 0, stream>>>(emis, amask, startT, trans, initv, Pmat);
  crf_combine<<<BB, 64, 0, stream>>>(emis, labels, amask, startT, endT, trans, initv, Pmat, llh);
  finalize<<<1, 64, 0, stream>>>(llh, out);
}

// Round 5
// 198.576 us; speedup vs baseline: 1.6227x; 1.6227x over previous
//
#include <hip/hip_runtime.h>
#include <cstdint>

// BertCRF: emissions = hidden @ cls_w + cls_b ; CRF NLL (num - logZ), loss = -mean
// B=64 S=512 H=768 L=9
#define BB 64
#define SS 512
#define HH 768
#define LL 9
#define NROWS (BB * SS)
#define NCHUNK 16
#define CLEN 32   // SS / NCHUNK

#define L2E 1.4426950408889634f
#define LN2 0.6931471805599453f
#define NEGINF (-1e30f)

typedef __attribute__((ext_vector_type(8))) short bf16x8;
typedef __attribute__((ext_vector_type(4))) float f32x4;

// f32 -> bf16, round-half-up (cheap 2-op; bias < 0.5 ulp, fine vs threshold)
__device__ inline short f2bf(float f) {
  uint32_t u = __builtin_bit_cast(uint32_t, f);
  return (short)((u + 0x8000u) >> 16);
}

// ---------------------------------------------------------------------------
// Kernel 0: pack cls_w into B-fragment order for mfma_f32_16x16x32_bf16.
// B layout: lane l holds B[k=(l>>4)*8+i][col=l&15], i=0..7 contiguous.
// wfrag[kt][lane] = 8 bf16 (16B). cols 9..15 zero-padded.
// ---------------------------------------------------------------------------
__global__ __launch_bounds__(256) void pack_w(const float* __restrict__ w,
                                              uint4* __restrict__ wfrag) {
  const int e = blockIdx.x * 256 + threadIdx.x;  // 24*64 = 1536 entries
  if (e >= 24 * 64) return;
  const int c = e >> 6, l = e & 63;
  const int col = l & 15, g = l >> 4;
  const int k0 = c * 32 + g * 8;
  uint32_t pk[4];
#pragma unroll
  for (int p = 0; p < 4; ++p) {
    const float lo = (col < LL) ? w[(k0 + 2 * p) * LL + col] : 0.f;
    const float hi = (col < LL) ? w[(k0 + 2 * p + 1) * LL + col] : 0.f;
    pk[p] = (uint32_t)(uint16_t)f2bf(lo) | ((uint32_t)(uint16_t)f2bf(hi) << 16);
  }
  wfrag[e] = make_uint4(pk[0], pk[1], pk[2], pk[3]);
}

// ---------------------------------------------------------------------------
// Kernel 1: emissions GEMM via MFMA. One wave = one 16-row M-tile; K-loop
// 24 x (k=32). A-frag: lane cluster {l,l+16,l+32,l+48} reads its row's 128B
// contiguous (2 full lines) -> 16 segments/instr, all bytes used. MFMA does
// the K-reduction (no shuffles, no LDS, no barriers). 2048 waves = 8/CU.
// C/D layout: col=lane&15, row=(lane>>4)*4+reg (m89-verified).
// ---------------------------------------------------------------------------
__global__ __launch_bounds__(256) void emis_gemm(
    const float* __restrict__ hidden, const uint4* __restrict__ wfrag,
    const float* __restrict__ bias, float* __restrict__ emis) {
  const int lane = threadIdx.x & 63;
  const int wv = threadIdx.x >> 6;
  const int m0 = (blockIdx.x * 4 + wv) * 16;
  const int g = lane >> 4;
  const int row = m0 + (lane & 15);
  const float4* __restrict__ hp =
      reinterpret_cast<const float4*>(hidden + (size_t)row * HH) + 2 * g;
  const bf16x8* __restrict__ bf = reinterpret_cast<const bf16x8*>(wfrag);

  f32x4 acc = {0.f, 0.f, 0.f, 0.f};
#pragma unroll 4
  for (int kt = 0; kt < 24; ++kt) {
    const float4 h0 = hp[kt * 8];
    const float4 h1 = hp[kt * 8 + 1];
    union { short s[8]; bf16x8 v; } a;
    a.s[0] = f2bf(h0.x); a.s[1] = f2bf(h0.y); a.s[2] = f2bf(h0.z); a.s[3] = f2bf(h0.w);
    a.s[4] = f2bf(h1.x); a.s[5] = f2bf(h1.y); a.s[6] = f2bf(h1.z); a.s[7] = f2bf(h1.w);
    const bf16x8 b = bf[kt * 64 + lane];
    acc = __builtin_amdgcn_mfma_f32_16x16x32_bf16(a.v, b, acc, 0, 0, 0);
  }
  const int col = lane & 15;
  if (col < LL) {
    const float bcol = bias[col];
#pragma unroll
    for (int r = 0; r < 4; ++r) {
      const int rr = m0 + g * 4 + r;
      emis[(size_t)rr * LL + col] = acc[r] + bcol;
    }
  }
}

// ---------------------------------------------------------------------------
// Kernel 2: CRF chunk scan (stage 1). Grid = 64 batches x 16 chunks.
// Block = 128 threads (2 waves). Chunk 0: real alpha recursion for steps
// 1..31 from init = start + em[0]. Chunks c>0: 9x9 log-matrix product of
// steps [32c, 32c+32) via 9 basis-row recursions. Wave 0 rows 0..6
// (lanes r*9+j), wave 1 rows 7..8 (lanes 0..17). Masked step == identity.
// ---------------------------------------------------------------------------
__global__ __launch_bounds__(128) void crf_chunk(
    const float* __restrict__ emis, const int* __restrict__ msk,
    const float* __restrict__ startT, const float* __restrict__ trans,
    float* __restrict__ initv, float* __restrict__ Pmat) {
  __shared__ float em_lds[CLEN * LL];
  __shared__ int mk_lds[CLEN];
  const int b = blockIdx.x >> 4;
  const int c = blockIdx.x & 15;
  const int tid = threadIdx.x;
  const int lane = tid & 63;
  const int wid = tid >> 6;

  const float* src = emis + ((size_t)b * SS + c * CLEN) * LL;
  for (int i = tid; i < CLEN * LL; i += 128) em_lds[i] = src[i];
  for (int i = tid; i < CLEN; i += 128) mk_lds[i] = msk[b * SS + c * CLEN + i];
  __syncthreads();

  int rloc = lane / 9;
  int j = lane - rloc * 9;
  if (rloc > 6) { rloc = 6; j = 8; }  // lane 63 (inactive) kept in-bounds
  const int rbase = rloc * 9;
  const bool active = (wid == 0) ? (lane < 63) : (lane < 18);
  const int r = wid * 7 + rloc;  // global row this lane-group computes

  float Tc[LL];
#pragma unroll
  for (int i = 0; i < LL; ++i) Tc[i] = trans[i * LL + j];

  float s;
  if (c == 0) s = startT[j] + em_lds[j];
  else s = (j == r) ? 0.f : NEGINF;
  const int t0 = (c == 0) ? 1 : 0;

  for (int t = t0; t < CLEN; ++t) {
    const float emj = em_lds[t * LL + j];
    const int mt = mk_lds[t];
    const float s0 = __shfl(s, rbase + 0), s1 = __shfl(s, rbase + 1), s2 = __shfl(s, rbase + 2);
    const float s3 = __shfl(s, rbase + 3), s4 = __shfl(s, rbase + 4), s5 = __shfl(s, rbase + 5);
    const float s6 = __shfl(s, rbase + 6), s7 = __shfl(s, rbase + 7), s8 = __shfl(s, rbase + 8);
    const float a0 = s0 + Tc[0], a1 = s1 + Tc[1], a2 = s2 + Tc[2];
    const float a3 = s3 + Tc[3], a4 = s4 + Tc[4], a5 = s5 + Tc[5];
    const float a6 = s6 + Tc[6], a7 = s7 + Tc[7], a8 = s8 + Tc[8];
    const float m = fmaxf(fmaxf(fmaxf(fmaxf(a0, a1), fmaxf(a2, a3)),
                                fmaxf(fmaxf(a4, a5), fmaxf(a6, a7))), a8);
    const float e =
        ((exp2f((a0 - m) * L2E) + exp2f((a1 - m) * L2E)) +
         (exp2f((a2 - m) * L2E) + exp2f((a3 - m) * L2E))) +
        ((exp2f((a4 - m) * L2E) + exp2f((a5 - m) * L2E)) +
         (exp2f((a6 - m) * L2E) + exp2f((a7 - m) * L2E))) +
        exp2f((a8 - m) * L2E);
    const float snew = m + LN2 * log2f(e) + emj;
    s = mt ? snew : s;
  }

  if (active) {
    if (c == 0) {
      if (wid == 0 && lane < LL) initv[b * LL + j] = s;
    } else {
      Pmat[((size_t)b * NCHUNK + c) * 81 + r * LL + j] = s;
    }
  }
}

// ---------------------------------------------------------------------------
// Kernel 3: per-batch combine (stage 2) + numerator. One 64-thread block
// per batch. Numerator: wave-parallel over timesteps + butterfly reduce.
// Denominator: alpha = initv, then 15 sequential vector x log-matrix
// combines (P staged in LDS), then lse with end transitions.
// ---------------------------------------------------------------------------
__global__ __launch_bounds__(64) void crf_combine(
    const float* __restrict__ emis, const int* __restrict__ labels,
    const int* __restrict__ msk, const float* __restrict__ startT,
    const float* __restrict__ endT, const float* __restrict__ trans,
    const float* __restrict__ initv, const float* __restrict__ Pmat,
    float* __restrict__ llh) {
  __shared__ float Pl[15 * 81];
  const int b = blockIdx.x;
  const int lane = threadIdx.x;
  const float* __restrict__ emb = emis + (size_t)b * SS * LL;
  const int* __restrict__ lab = labels + b * SS;
  const int* __restrict__ mk = msk + b * SS;

  const float* Pb = Pmat + (size_t)b * NCHUNK * 81 + 81;
  for (int i = lane; i < 15 * 81; i += 64) Pl[i] = Pb[i];

  // ---- numerator ----
  float acc = 0.f;
  int msum = 0;
  for (int t = lane; t < SS; t += 64) {
    int tg = lab[t]; if (tg == -100) tg = 0;
    const int mt = mk[t];
    msum += mt;
    if (t == 0) {
      acc += startT[tg] + emb[tg];
    } else {
      int tp = lab[t - 1]; if (tp == -100) tp = 0;
      acc += (trans[tp * LL + tg] + emb[t * LL + tg]) * (float)mt;
    }
  }
#pragma unroll
  for (int off = 32; off; off >>= 1) {
    acc += __shfl_xor(acc, off);
    msum += __shfl_xor(msum, off);
  }
  const int seq_end = msum - 1;
  int lt = lab[seq_end]; if (lt == -100) lt = 0;
  const float num = acc + endT[lt];

  __syncthreads();

  // ---- denominator ----
  const int j = (lane < LL) ? lane : 8;
  float a = initv[b * LL + j];
#pragma unroll 1
  for (int c = 0; c < 15; ++c) {
    const float* P = &Pl[c * 81];
    const float s0 = __shfl(a, 0), s1 = __shfl(a, 1), s2 = __shfl(a, 2);
    const float s3 = __shfl(a, 3), s4 = __shfl(a, 4), s5 = __shfl(a, 5);
    const float s6 = __shfl(a, 6), s7 = __shfl(a, 7), s8 = __shfl(a, 8);
    const float a0 = s0 + P[0 * LL + j], a1 = s1 + P[1 * LL + j], a2 = s2 + P[2 * LL + j];
    const float a3 = s3 + P[3 * LL + j], a4 = s4 + P[4 * LL + j], a5 = s5 + P[5 * LL + j];
    const float a6 = s6 + P[6 * LL + j], a7 = s7 + P[7 * LL + j], a8 = s8 + P[8 * LL + j];
    const float m = fmaxf(fmaxf(fmaxf(fmaxf(a0, a1), fmaxf(a2, a3)),
                                fmaxf(fmaxf(a4, a5), fmaxf(a6, a7))), a8);
    const float e =
        ((exp2f((a0 - m) * L2E) + exp2f((a1 - m) * L2E)) +
         (exp2f((a2 - m) * L2E) + exp2f((a3 - m) * L2E))) +
        ((exp2f((a4 - m) * L2E) + exp2f((a5 - m) * L2E)) +
         (exp2f((a6 - m) * L2E) + exp2f((a7 - m) * L2E))) +
        exp2f((a8 - m) * L2E);
    a = m + LN2 * log2f(e);
  }
  a += endT[j];
  {
    const float s0 = __shfl(a, 0), s1 = __shfl(a, 1), s2 = __shfl(a, 2);
    const float s3 = __shfl(a, 3), s4 = __shfl(a, 4), s5 = __shfl(a, 5);
    const float s6 = __shfl(a, 6), s7 = __shfl(a, 7), s8 = __shfl(a, 8);
    const float m = fmaxf(fmaxf(fmaxf(fmaxf(s0, s1), fmaxf(s2, s3)),
                                fmaxf(fmaxf(s4, s5), fmaxf(s6, s7))), s8);
    const float e =
        ((exp2f((s0 - m) * L2E) + exp2f((s1 - m) * L2E)) +
         (exp2f((s2 - m) * L2E) + exp2f((s3 - m) * L2E))) +
        ((exp2f((s4 - m) * L2E) + exp2f((s5 - m) * L2E)) +
         (exp2f((s6 - m) * L2E) + exp2f((s7 - m) * L2E))) +
        exp2f((s8 - m) * L2E);
    const float denom = m + LN2 * log2f(e);
    if (lane == 0) llh[b] = num - denom;
  }
}

// ---------------------------------------------------------------------------
// Kernel 4: loss = -mean(llh)
// ---------------------------------------------------------------------------
__global__ __launch_bounds__(64) void finalize(const float* __restrict__ llh,
                                               float* __restrict__ out) {
  float v = llh[threadIdx.x];
#pragma unroll
  for (int off = 32; off; off >>= 1) v += __shfl_xor(v, off);
  if (threadIdx.x == 0) out[0] = -v * (1.0f / BB);
}

extern "C" void kernel_launch(void* const* d_in, const int* in_sizes, int n_in,
                              void* d_out, int out_size, void* d_ws, size_t ws_size,
                              hipStream_t stream) {
  const float* hidden = (const float*)d_in[0];
  const float* cls_w  = (const float*)d_in[1];
  const float* cls_b  = (const float*)d_in[2];
  const float* startT = (const float*)d_in[3];
  const float* endT   = (const float*)d_in[4];
  const float* trans  = (const float*)d_in[5];
  const int* labels   = (const int*)d_in[6];
  const int* amask    = (const int*)d_in[7];

  float* out = (float*)d_out;
  float* emis = out + 1;  // output layout: [loss][emissions B*S*L]

  float* llh = (float*)d_ws;            // 64 floats
  float* initv = llh + 64;              // 64*9
  float* Pmat = initv + 64 * LL;        // 64*16*81 = 82944
  uint4* wfrag = (uint4*)(Pmat + (size_t)BB * NCHUNK * 81);  // 24KB, 16B-aligned

  pack_w<<<6, 256, 0, stream>>>(cls_w, wfrag);
  emis_gemm<<<NROWS / 64, 256, 0, stream>>>(hidden, wfrag, cls_b, emis);
  crf_chunk<<<BB * NCHUNK, 128, 0, stream>>>(emis, amask, startT, trans, initv, Pmat);
  crf_combine<<<BB, 64, 0, stream>>>(emis, labels, amask, startT, endT, trans, initv, Pmat, llh);
  finalize<<<1, 64, 0, stream>>>(llh, out);
}